// Round 5
// baseline (328.487 us; speedup 1.0000x reference)
//
#include <hip/hip_runtime.h>
#include <hip/hip_bf16.h>
#include <math.h>

#define B_DIM   4096
#define IN_DIM  4096
#define OUT_DIM 4096

typedef __attribute__((ext_vector_type(8))) short  short8;   // 8 x bf16 = 4 VGPRs
typedef __attribute__((ext_vector_type(4))) float  floatx4;  // MFMA 16x16 accum

__device__ __forceinline__ ushort f2bf(float f) {
    unsigned b = __float_as_uint(f);
    return (ushort)((b + 0x7fffu + ((b >> 16) & 1u)) >> 16);   // RNE
}

// ---- fused: x fp32 -> bf16  AND  fp64 column sums of x (device-scope atomics) ----
// grid (4, 64): bx -> 1024-col slab (4 cols/thread), by -> 64-row chunk.
// 64 atomics/column (was 256) -> 4x less L2 serialization on the sum lines.
__global__ void cvt_x_colsum(const float* __restrict__ x, ushort* __restrict__ xb,
                             double* __restrict__ xbar_sum) {
    int c0 = blockIdx.x * 1024 + threadIdx.x * 4;
    int r0 = blockIdx.y * 64;
    double s0 = 0, s1 = 0, s2 = 0, s3 = 0;
#pragma unroll 8
    for (int r = 0; r < 64; ++r) {
        size_t off = (size_t)(r0 + r) * IN_DIM + c0;
        float4 v = *(const float4*)(x + off);
        ushort4 o;
        o.x = f2bf(v.x); o.y = f2bf(v.y); o.z = f2bf(v.z); o.w = f2bf(v.w);
        *(ushort4*)(xb + off) = o;
        s0 += (double)v.x; s1 += (double)v.y; s2 += (double)v.z; s3 += (double)v.w;
    }
    double* p = xbar_sum + c0;
    atomicAdd(p + 0, s0); atomicAdd(p + 1, s1);
    atomicAdd(p + 2, s2); atomicAdd(p + 3, s3);
}

// ---- fused: W fp32 -> bf16  AND  means[o] = dot(xbar,W[o,:]) + b[o] -> idx[o] ----
__global__ void cvt_w_means(const float* __restrict__ W, const float* __restrict__ bias,
                            const double* __restrict__ xbar_sum, ushort* __restrict__ wb,
                            int* __restrict__ idx) {
    __shared__ double red4[4];
    int o = blockIdx.x;
    size_t base = (size_t)o * IN_DIM;
    double s = 0.0;
#pragma unroll
    for (int j = 0; j < 4; ++j) {
        int i = j * 1024 + threadIdx.x * 4;
        float4 v = *(const float4*)(W + base + i);
        ushort4 ob;
        ob.x = f2bf(v.x); ob.y = f2bf(v.y); ob.z = f2bf(v.z); ob.w = f2bf(v.w);
        *(ushort4*)(wb + base + i) = ob;
        double2 xv0 = *(const double2*)(xbar_sum + i);
        double2 xv1 = *(const double2*)(xbar_sum + i + 2);
        s += (double)v.x * xv0.x + (double)v.y * xv0.y
           + (double)v.z * xv1.x + (double)v.w * xv1.y;
    }
#pragma unroll
    for (int off = 32; off; off >>= 1) s += __shfl_down(s, off, 64);
    if ((threadIdx.x & 63) == 0) red4[threadIdx.x >> 6] = s;
    __syncthreads();
    if (threadIdx.x == 0) {
        double tot = red4[0] + red4[1] + red4[2] + red4[3];
        float mf = (float)(tot * (1.0 / (double)B_DIM) + (double)bias[o]);
        float md = fmodf(mf, 3.0f);
        if (md < 0.0f) md += 3.0f;
        idx[o] = (int)md;
    }
}

// ---- bf16 MFMA GEMM: 128x256 tile, BK=32, 3-deep counted-vmcnt ring,
//      2 blocks/CU for cross-block DS<->MFMA overlap ----
// 256 threads = 4 waves; every wave covers all 128 M rows and one 64-col N
// quarter (A fragments shared across waves). acc[8][4] = 128 VGPR/lane.
// LDS = 3 slots x (A 8KB + B 16KB) = 72 KiB -> 2 blocks/CU (144 <= 160 KiB).
// Per K-tile kt: [wait vmcnt(6); s_barrier; stage kt+2; 12 ds_read_b128;
// setprio(1) 32 MFMA setprio(0)]. Gate leaves tile kt+1's 6 loads in flight
// (never 0 until the tail). With 2 resident blocks per CU, one block's read
// burst overlaps the other's MFMA burst (m114-style TLP overlap) -- this is
// what the 1-block/CU 256^2 layout structurally could not do.
// Ring safety: stage(kt+2) targets slot (kt+2)%3 == (kt-1)%3, whose reads
// retired before this iteration's head barrier (each wave's slot-(kt-1) reads
// were lgkmcnt-consumed by its MFMAs before it arrived at that barrier).
// Gate correctness: per-wave vmcnt counts its own loads; wait-then-barrier
// means every wave's share of slot kt has landed before any wave reads it.
// Swizzle (64B rows, 4 x 16B granules): LDS granule pg holds logical
// pg ^ ((r>>1)&3); applied to per-lane GLOBAL src (linear LDS dest, as
// global_load_lds requires); fragment address uses the same XOR.
// Verified 0 bank conflicts in this form (R1 measurement).
__global__ void __launch_bounds__(256, 2) gemm_bt_act(
    const ushort* __restrict__ A,   // [M,K] bf16 bits (x)
    const ushort* __restrict__ Bt,  // [N,K] bf16 bits (W)
    const float*  __restrict__ bias,
    const int*    __restrict__ idx,
    float*        __restrict__ out) {
    // per slot: A = 128*32 = 4096 ushorts (8KB), B = 256*32 = 8192 ushorts (16KB)
    __shared__ __align__(16) ushort lds[3][12288];

    const int t    = threadIdx.x;
    const int w    = t >> 6;      // 0..3 -> N quarter
    const int l    = t & 63;
    const int quad = l >> 4;
    const int lrow = l & 15;

    // XCD-bijective swizzle: 512 wgs; tile grid 32(M) x 16(N); each XCD owns
    // a contiguous 8x8 tile region (4 XCD-rows x 2 XCD-cols).
    const int b   = blockIdx.x;
    const int xcd = b & 7;
    const int p   = b >> 3;                        // 0..63
    const int m0  = ((xcd >> 1) * 8 + (p >> 3)) * 128;
    const int n0  = ((xcd & 1) * 8 + (p & 7)) * 256;

    const int K = IN_DIM;

    // staging: per-thread K-invariant offsets (16B granules, 64B rows)
    // A: 512 granules (2/thread); B: 1024 granules (4/thread)
    size_t aoff[2];  int alds[2];
    size_t boff[4];  int blds[4];
#pragma unroll
    for (int j = 0; j < 2; ++j) {
        int c  = j * 256 + t;                      // 0..511
        int r  = c >> 2;                           // 0..127
        int pg = (c & 3) ^ ((r >> 1) & 3);
        aoff[j] = (size_t)(m0 + r) * K + pg * 8;
        alds[j] = c * 8;
    }
#pragma unroll
    for (int j = 0; j < 4; ++j) {
        int c  = j * 256 + t;                      // 0..1023
        int r  = c >> 2;                           // 0..255
        int pg = (c & 3) ^ ((r >> 1) & 3);
        boff[j] = (size_t)(n0 + r) * K + pg * 8;
        blds[j] = 4096 + c * 8;                    // B region after A (4096 ushorts)
    }

    // fragment byte offsets; (r>>1)&3 == (lrow>>1)&3 (row bases are %16==0)
    const int kbsw  = (quad ^ ((lrow >> 1) & 3)) * 16;
    const int aBase = lrow * 64 + kbsw;                      // + mi*1024
    const int bBase = 8192 + (w * 64 + lrow) * 64 + kbsw;    // + ni*1024 (bytes)

    floatx4 acc[8][4] = {};

#define STAGE(kt, slot)                                                          \
    {                                                                             \
        const size_t ks = (size_t)(kt) * 32;                                      \
        _Pragma("unroll")                                                         \
        for (int j = 0; j < 2; ++j)                                               \
            __builtin_amdgcn_global_load_lds(                                     \
                (__attribute__((address_space(1))) void*)(A + aoff[j] + ks),      \
                (__attribute__((address_space(3))) void*)(&lds[slot][alds[j]]),   \
                16, 0, 0);                                                        \
        _Pragma("unroll")                                                         \
        for (int j = 0; j < 4; ++j)                                               \
            __builtin_amdgcn_global_load_lds(                                     \
                (__attribute__((address_space(1))) void*)(Bt + boff[j] + ks),     \
                (__attribute__((address_space(3))) void*)(&lds[slot][blds[j]]),   \
                16, 0, 0);                                                        \
    }

    // prologue: stage tiles 0,1 (12 loads/thread in flight)
    STAGE(0, 0);
    STAGE(1, 1);

#pragma unroll 1
    for (int kt = 0; kt < 128; ++kt) {
        // drain through tile kt (own loads); barrier -> whole slot kt landed
        if (kt < 127) { asm volatile("s_waitcnt vmcnt(6)" ::: "memory"); }
        else          { asm volatile("s_waitcnt vmcnt(0)" ::: "memory"); }
        __builtin_amdgcn_s_barrier();

        if (kt + 2 < 128) STAGE(kt + 2, (kt + 2) % 3);

        const char* s = (const char*)&lds[kt % 3][0];
        short8 af[8], bf[4];
#pragma unroll
        for (int mi = 0; mi < 8; ++mi)
            af[mi] = *(const short8*)(s + aBase + mi * 1024);
#pragma unroll
        for (int ni = 0; ni < 4; ++ni)
            bf[ni] = *(const short8*)(s + bBase + ni * 1024);

        __builtin_amdgcn_s_setprio(1);
#pragma unroll
        for (int mi = 0; mi < 8; ++mi)
#pragma unroll
            for (int ni = 0; ni < 4; ++ni)
                acc[mi][ni] = __builtin_amdgcn_mfma_f32_16x16x32_bf16(
                    af[mi], bf[ni], acc[mi][ni], 0, 0, 0);
        __builtin_amdgcn_s_setprio(0);
    }
#undef STAGE

    // epilogue: y = acc + bias[col]; branchless activation by idx[col]
    // C/D mapping: col = lane&15, row = quad*4 + reg
#pragma unroll
    for (int ni = 0; ni < 4; ++ni) {
        int   col     = n0 + w * 64 + ni * 16 + lrow;
        int   id      = idx[col];
        float bv      = bias[col];
        float aa      = (id == 1) ? -2.0f : -1.0f;
        bool  isrelu  = (id == 0);
        bool  istanh  = (id == 1);
#pragma unroll
        for (int mi = 0; mi < 8; ++mi) {
            int rowb = m0 + mi * 16 + quad * 4;
#pragma unroll
            for (int r = 0; r < 4; ++r) {
                float y   = acc[mi][ni][r] + bv;
                float e   = __expf(aa * y);                    // v_exp_f32 path
                float sg  = __builtin_amdgcn_rcpf(1.0f + e);   // v_rcp_f32
                float act = istanh ? fmaf(2.0f, sg, -1.0f) : sg;
                float v   = isrelu ? fmaxf(y, 0.0f) : act;
                out[(size_t)(rowb + r) * OUT_DIM + col] = v;
            }
        }
    }
}

extern "C" void kernel_launch(void* const* d_in, const int* in_sizes, int n_in,
                              void* d_out, int out_size, void* d_ws, size_t ws_size,
                              hipStream_t stream) {
    const float* x = (const float*)d_in[0];
    const float* W = (const float*)d_in[1];
    const float* b = (const float*)d_in[2];
    float* out = (float*)d_out;

    char* ws = (char*)d_ws;
    ushort* xb   = (ushort*)(ws);                        // 32 MB
    ushort* wb   = (ushort*)(ws + 33554432);             // 32 MB
    double* xbar = (double*)(ws + 67108864);             // 32 KB (column sums)
    int*    idx  = (int*)   (ws + 67108864 + 32768);     // 16 KB

    hipMemsetAsync(xbar, 0, IN_DIM * sizeof(double), stream);
    cvt_x_colsum<<<dim3(4, 64), 256, 0, stream>>>(x, xb, xbar);
    cvt_w_means<<<4096, 256, 0, stream>>>(W, b, xbar, wb, idx);
    gemm_bt_act<<<512, 256, 0, stream>>>(xb, wb, b, idx, out);
}

// Round 6
// 310.268 us; speedup vs baseline: 1.0587x; 1.0587x over previous
//
#include <hip/hip_runtime.h>
#include <hip/hip_bf16.h>
#include <math.h>

#define B_DIM   4096
#define IN_DIM  4096
#define OUT_DIM 4096

typedef __attribute__((ext_vector_type(8))) short  short8;   // 8 x bf16 = 4 VGPRs
typedef __attribute__((ext_vector_type(4))) float  floatx4;  // MFMA 16x16 accum

__device__ __forceinline__ ushort f2bf(float f) {
    unsigned b = __float_as_uint(f);
    return (ushort)((b + 0x7fffu + ((b >> 16) & 1u)) >> 16);   // RNE
}

// ---- fused: x fp32 -> bf16  AND  fp64 column sums of x (device-scope atomics) ----
// grid (4, 256): bx -> 1024-col slab (4 cols/thread), by -> 16-row chunk.
// (R5's (4,64)/64-rows variant regressed ~15us -- reverted to this R2 config.)
__global__ void cvt_x_colsum(const float* __restrict__ x, ushort* __restrict__ xb,
                             double* __restrict__ xbar_sum) {
    int c0 = blockIdx.x * 1024 + threadIdx.x * 4;
    int r0 = blockIdx.y * 16;
    double s0 = 0, s1 = 0, s2 = 0, s3 = 0;
#pragma unroll 4
    for (int r = 0; r < 16; ++r) {
        size_t off = (size_t)(r0 + r) * IN_DIM + c0;
        float4 v = *(const float4*)(x + off);
        ushort4 o;
        o.x = f2bf(v.x); o.y = f2bf(v.y); o.z = f2bf(v.z); o.w = f2bf(v.w);
        *(ushort4*)(xb + off) = o;
        s0 += (double)v.x; s1 += (double)v.y; s2 += (double)v.z; s3 += (double)v.w;
    }
    double* p = xbar_sum + c0;
    atomicAdd(p + 0, s0); atomicAdd(p + 1, s1);
    atomicAdd(p + 2, s2); atomicAdd(p + 3, s3);
}

// ---- fused: W fp32 -> bf16  AND  means[o] = dot(xbar,W[o,:]) + b[o] -> idx[o] ----
__global__ void cvt_w_means(const float* __restrict__ W, const float* __restrict__ bias,
                            const double* __restrict__ xbar_sum, ushort* __restrict__ wb,
                            int* __restrict__ idx) {
    __shared__ double red4[4];
    int o = blockIdx.x;
    size_t base = (size_t)o * IN_DIM;
    double s = 0.0;
#pragma unroll
    for (int j = 0; j < 4; ++j) {
        int i = j * 1024 + threadIdx.x * 4;
        float4 v = *(const float4*)(W + base + i);
        ushort4 ob;
        ob.x = f2bf(v.x); ob.y = f2bf(v.y); ob.z = f2bf(v.z); ob.w = f2bf(v.w);
        *(ushort4*)(wb + base + i) = ob;
        double2 xv0 = *(const double2*)(xbar_sum + i);
        double2 xv1 = *(const double2*)(xbar_sum + i + 2);
        s += (double)v.x * xv0.x + (double)v.y * xv0.y
           + (double)v.z * xv1.x + (double)v.w * xv1.y;
    }
#pragma unroll
    for (int off = 32; off; off >>= 1) s += __shfl_down(s, off, 64);
    if ((threadIdx.x & 63) == 0) red4[threadIdx.x >> 6] = s;
    __syncthreads();
    if (threadIdx.x == 0) {
        double tot = red4[0] + red4[1] + red4[2] + red4[3];
        float mf = (float)(tot * (1.0 / (double)B_DIM) + (double)bias[o]);
        float md = fmodf(mf, 3.0f);
        if (md < 0.0f) md += 3.0f;
        idx[o] = (int)md;
    }
}

// ---- bf16 MFMA GEMM: faithful m201 8-phase reconstruction ----
// 256x256 tile, BK=64, 512 thr = 8 waves (2M x 4N), wave output 128x64.
// LDS = 2 slots (K-tile parity) x (A 32KB + B 32KB) = 128 KiB, half-tile
// staging (128 rows x 64 cols = 16KB = 2 gloads/thread).
// Per K-tile t (slot s=t&1): 4 phases, each = one C-quadrant x K=64 (16 MFMA),
// with operand REUSE across phases (order Q00->Q01->Q11->Q10 minimizes live
// ranges: peak operand-live 64 VGPR + 128 acc):
//   P1: read a0(A mh0,8) + b0(B nh0,4) [12 -> lgkmcnt(8) hint]; stage A_lo(t+1)->o
//   P2: read b1(B nh1,4);                                       stage A_hi(t+1)->o
//   P3: read a1(A mh1,8);                                       stage B_lo(t+2)->s
//   P4: no reads;                     stage B_hi(t+2)->s; GATE vmcnt(4)
// phase shape: [reads; stage] barrier; lgkmcnt(0); sched_barrier(0) (rule 18,
// ONLY here); setprio(1); 16 MFMA; setprio(0); barrier.
// Write-after-read safety is closed by the CLOSING barrier: every staged
// region's readers completed their lgkmcnt(0) before the previous phase's
// closing barrier; the stage is issued after it. (A_lo readers=wm0 waves,
// done P3(t-1); B_lo readers=wn{0,1} waves, done P2(t).)
// Gate ledger (steady): outstanding at P4 = A_lo(t+1),A_hi(t+1),B_lo(t+2),
// B_hi(t+2) = 8 loads; vmcnt(4) -> tile t+1 fully landed, B(t+2) in flight
// (never drains to 0). Tail: t>=62 stages predicated off, gate vmcnt(0).
// Prologue: B_lo(0),B_hi(0),A_lo(0),A_hi(0),B_lo(1),B_hi(1); vmcnt(4); barrier.
// Swizzle (128B rows, 8x16B granules): LDS granule pg holds logical pg^(row&7),
// applied on the per-lane GLOBAL address (linear LDS dest); fragment addr uses
// the same XOR; ks1 = byte-addr ^ 64. Verified 0 bank conflicts (R4).
__global__ void __launch_bounds__(512, 2) gemm_bt_act(
    const ushort* __restrict__ A,   // [M,K] bf16 bits (x)
    const ushort* __restrict__ Bt,  // [N,K] bf16 bits (W)
    const float*  __restrict__ bias,
    const int*    __restrict__ idx,
    float*        __restrict__ out) {
    __shared__ __align__(16) ushort lds[2][2][16384];   // [slot][A,B][32KB]

    const int t    = threadIdx.x;
    const int w    = t >> 6;
    const int l    = t & 63;
    const int quad = l >> 4;
    const int lrow = l & 15;
    const int wm   = w >> 2;      // 0..1 -> M half
    const int wn   = w & 3;       // 0..3 -> N quarter

    // XCD-bijective swizzle: 256 wgs; each XCD owns a contiguous 4x8 tile region
    const int b   = blockIdx.x;
    const int xcd = b & 7;
    const int p   = b >> 3;
    const int m0  = ((xcd >> 1) * 4 + (p >> 3)) * 256;
    const int n0  = ((xcd & 1) * 8 + (p & 7)) * 256;

    const int K = IN_DIM;

    // staging: per-thread K-invariant offsets. chunk c in 0..1023 per half-tile:
    // r = c>>3 (half-local row 0..127), pg = (c&7)^(r&7) pre-swizzled granule.
    size_t aoffs[2], boffs[2];
    int    ldsoff[2];
#pragma unroll
    for (int j = 0; j < 2; ++j) {
        int c  = j * 512 + t;
        int r  = c >> 3;
        int lg = (c & 7) ^ (r & 7);
        aoffs[j]  = (size_t)(m0 + r) * K + lg * 8;
        boffs[j]  = (size_t)(n0 + r) * K + lg * 8;
        ldsoff[j] = c * 8;                       // ushorts within a 16KB half
    }

#define STAGEH(ptr, offs, mat, half, kt, slot)                                   \
    {                                                                             \
        _Pragma("unroll")                                                         \
        for (int j = 0; j < 2; ++j)                                               \
            __builtin_amdgcn_global_load_lds(                                     \
                (__attribute__((address_space(1))) void*)((ptr) + offs[j] +       \
                    (size_t)(half) * 128 * IN_DIM + (size_t)(kt) * 64),           \
                (__attribute__((address_space(3))) void*)(&lds[slot][mat][(half) * 8192 + ldsoff[j]]), \
                16, 0, 0);                                                        \
    }

    // fragment byte offsets (ks0): +mh*8192, +mi*2048 (A); +nh*4096, +ni*2048 (B);
    // ks1 = ^64 (granule bit2; XOR-compatible since higher offsets don't touch bit6)
    const int gsw = (quad ^ (lrow & 7)) << 4;
    const int aB  = (wm * 128 + lrow) * 128 + gsw;
    const int bB  = (wn * 64  + lrow) * 128 + gsw;

    floatx4 acc[8][4] = {};

    // prologue (steady-state stage order): B(0), A(0), B(1); gate; barrier
    STAGEH(Bt, boffs, 1, 0, 0, 0); STAGEH(Bt, boffs, 1, 1, 0, 0);
    STAGEH(A,  aoffs, 0, 0, 0, 0); STAGEH(A,  aoffs, 0, 1, 0, 0);
    STAGEH(Bt, boffs, 1, 0, 1, 1); STAGEH(Bt, boffs, 1, 1, 1, 1);
    asm volatile("s_waitcnt vmcnt(4)" ::: "memory");
    __builtin_amdgcn_s_barrier();

#pragma unroll 1
    for (int kt = 0; kt < 64; ++kt) {
        const int s = kt & 1, o = s ^ 1;
        const char* sA = (const char*)&lds[s][0][0];
        const char* sB = (const char*)&lds[s][1][0];
        short8 a0[4][2], a1[4][2], b0[2][2], b1[2][2];

        // ---- P1: read a0 (A mh0, 8) + b0 (B nh0, 4); stage A_lo(kt+1) ----
#pragma unroll
        for (int mi = 0; mi < 4; ++mi)
#pragma unroll
            for (int ks = 0; ks < 2; ++ks)
                a0[mi][ks] = *(const short8*)(sA + ((aB + mi * 2048) ^ (ks * 64)));
#pragma unroll
        for (int ni = 0; ni < 2; ++ni)
#pragma unroll
            for (int ks = 0; ks < 2; ++ks)
                b0[ni][ks] = *(const short8*)(sB + ((bB + ni * 2048) ^ (ks * 64)));
        if (kt + 1 < 64) STAGEH(A, aoffs, 0, 0, kt + 1, o);
        asm volatile("s_waitcnt lgkmcnt(8)" ::: "memory");
        __builtin_amdgcn_s_barrier();
        asm volatile("s_waitcnt lgkmcnt(0)" ::: "memory");
        __builtin_amdgcn_sched_barrier(0);
        __builtin_amdgcn_s_setprio(1);
#pragma unroll
        for (int ks = 0; ks < 2; ++ks)
#pragma unroll
            for (int mi = 0; mi < 4; ++mi)
#pragma unroll
                for (int ni = 0; ni < 2; ++ni)
                    acc[mi][ni] = __builtin_amdgcn_mfma_f32_16x16x32_bf16(
                        a0[mi][ks], b0[ni][ks], acc[mi][ni], 0, 0, 0);
        __builtin_amdgcn_s_setprio(0);
        __builtin_amdgcn_s_barrier();

        // ---- P2: read b1 (B nh1, 4); stage A_hi(kt+1); Q01 = a0 x b1 ----
#pragma unroll
        for (int ni = 0; ni < 2; ++ni)
#pragma unroll
            for (int ks = 0; ks < 2; ++ks)
                b1[ni][ks] = *(const short8*)(sB + ((bB + 4096 + ni * 2048) ^ (ks * 64)));
        if (kt + 1 < 64) STAGEH(A, aoffs, 0, 1, kt + 1, o);
        __builtin_amdgcn_s_barrier();
        asm volatile("s_waitcnt lgkmcnt(0)" ::: "memory");
        __builtin_amdgcn_sched_barrier(0);
        __builtin_amdgcn_s_setprio(1);
#pragma unroll
        for (int ks = 0; ks < 2; ++ks)
#pragma unroll
            for (int mi = 0; mi < 4; ++mi)
#pragma unroll
                for (int ni = 0; ni < 2; ++ni)
                    acc[mi][ni + 2] = __builtin_amdgcn_mfma_f32_16x16x32_bf16(
                        a0[mi][ks], b1[ni][ks], acc[mi][ni + 2], 0, 0, 0);
        __builtin_amdgcn_s_setprio(0);
        __builtin_amdgcn_s_barrier();

        // ---- P3: read a1 (A mh1, 8); stage B_lo(kt+2); Q11 = a1 x b1 ----
#pragma unroll
        for (int mi = 0; mi < 4; ++mi)
#pragma unroll
            for (int ks = 0; ks < 2; ++ks)
                a1[mi][ks] = *(const short8*)(sA + ((aB + 8192 + mi * 2048) ^ (ks * 64)));
        if (kt + 2 < 64) STAGEH(Bt, boffs, 1, 0, kt + 2, s);
        __builtin_amdgcn_s_barrier();
        asm volatile("s_waitcnt lgkmcnt(0)" ::: "memory");
        __builtin_amdgcn_sched_barrier(0);
        __builtin_amdgcn_s_setprio(1);
#pragma unroll
        for (int ks = 0; ks < 2; ++ks)
#pragma unroll
            for (int mi = 0; mi < 4; ++mi)
#pragma unroll
                for (int ni = 0; ni < 2; ++ni)
                    acc[mi + 4][ni + 2] = __builtin_amdgcn_mfma_f32_16x16x32_bf16(
                        a1[mi][ks], b1[ni][ks], acc[mi + 4][ni + 2], 0, 0, 0);
        __builtin_amdgcn_s_setprio(0);
        __builtin_amdgcn_s_barrier();

        // ---- P4: no reads; stage B_hi(kt+2); GATE; Q10 = a1 x b0 ----
        if (kt + 2 < 64) STAGEH(Bt, boffs, 1, 1, kt + 2, s);
        if (kt < 62) { asm volatile("s_waitcnt vmcnt(4)" ::: "memory"); }
        else         { asm volatile("s_waitcnt vmcnt(0)" ::: "memory"); }
        __builtin_amdgcn_s_barrier();
        __builtin_amdgcn_s_setprio(1);
#pragma unroll
        for (int ks = 0; ks < 2; ++ks)
#pragma unroll
            for (int mi = 0; mi < 4; ++mi)
#pragma unroll
                for (int ni = 0; ni < 2; ++ni)
                    acc[mi + 4][ni] = __builtin_amdgcn_mfma_f32_16x16x32_bf16(
                        a1[mi][ks], b0[ni][ks], acc[mi + 4][ni], 0, 0, 0);
        __builtin_amdgcn_s_setprio(0);
        __builtin_amdgcn_s_barrier();
    }
#undef STAGEH

    // epilogue: y = acc + bias[col]; branchless activation by idx[col]
    // C/D mapping: col = lane&15, row = quad*4 + reg
#pragma unroll
    for (int ni = 0; ni < 4; ++ni) {
        int   col     = n0 + wn * 64 + ni * 16 + lrow;
        int   id      = idx[col];
        float bv      = bias[col];
        float aa      = (id == 1) ? -2.0f : -1.0f;
        bool  isrelu  = (id == 0);
        bool  istanh  = (id == 1);
#pragma unroll
        for (int mi = 0; mi < 8; ++mi) {
            int rowb = m0 + wm * 128 + mi * 16 + quad * 4;
#pragma unroll
            for (int r = 0; r < 4; ++r) {
                float y   = acc[mi][ni][r] + bv;
                float e   = __expf(aa * y);                    // v_exp_f32 path
                float sg  = __builtin_amdgcn_rcpf(1.0f + e);   // v_rcp_f32
                float act = istanh ? fmaf(2.0f, sg, -1.0f) : sg;
                float v   = isrelu ? fmaxf(y, 0.0f) : act;
                out[(size_t)(rowb + r) * OUT_DIM + col] = v;
            }
        }
    }
}

extern "C" void kernel_launch(void* const* d_in, const int* in_sizes, int n_in,
                              void* d_out, int out_size, void* d_ws, size_t ws_size,
                              hipStream_t stream) {
    const float* x = (const float*)d_in[0];
    const float* W = (const float*)d_in[1];
    const float* b = (const float*)d_in[2];
    float* out = (float*)d_out;

    char* ws = (char*)d_ws;
    ushort* xb   = (ushort*)(ws);                        // 32 MB
    ushort* wb   = (ushort*)(ws + 33554432);             // 32 MB
    double* xbar = (double*)(ws + 67108864);             // 32 KB (column sums)
    int*    idx  = (int*)   (ws + 67108864 + 32768);     // 16 KB

    hipMemsetAsync(xbar, 0, IN_DIM * sizeof(double), stream);
    cvt_x_colsum<<<dim3(4, 256), 256, 0, stream>>>(x, xb, xbar);
    cvt_w_means<<<4096, 256, 0, stream>>>(W, b, xbar, wb, idx);
    gemm_bt_act<<<256, 512, 0, stream>>>(xb, wb, b, idx, out);
}